// Round 6
// baseline (222.005 us; speedup 1.0000x reference)
//
#include <hip/hip_runtime.h>

typedef _Float16 f16;
typedef _Float16 f16x8 __attribute__((ext_vector_type(8)));
typedef _Float16 f16x4 __attribute__((ext_vector_type(4)));
typedef __fp16 h16x2 __attribute__((ext_vector_type(2)));
typedef float f32x4 __attribute__((ext_vector_type(4)));

#define MFMA32(a, b, c) __builtin_amdgcn_mfma_f32_16x16x32_f16((a), (b), (c), 0, 0, 0)
#define MFMA16(a, b, c) __builtin_amdgcn_mfma_f32_16x16x16f16((a), (b), (c), 0, 0, 0)

static constexpr int Bb = 2, T = 2048, H = 1024, NH = 16, HD = 64;
static constexpr int M = Bb * T;      // 4096 rows
static constexpr int NQKV = 3 * H;    // 3072
// fold 1/sqrt(64) * log2(e) into Wq/bq so P = 2^S via raw v_exp_f32
#define QSCALE 0.1803368801111f

// async global->LDS, 16B per lane; LDS dest = wave-uniform base + lane*16
__device__ __forceinline__ void gload_lds16(const void* g, void* l) {
  __builtin_amdgcn_global_load_lds(
      (const __attribute__((address_space(1))) void*)g,
      (__attribute__((address_space(3))) void*)l, 16, 0, 0);
}

// ---------- fused pack kernel ----------
// blocks [0,4096): x f32->f16; [4096,5120): 4 weight transposes; [5120,5132): bias
__global__ __launch_bounds__(256) void pack_all(const float* __restrict__ x,
                                                const float* __restrict__ Wq,
                                                const float* __restrict__ Wk,
                                                const float* __restrict__ Wv,
                                                const float* __restrict__ Wo,
                                                const float* __restrict__ bq,
                                                const float* __restrict__ bk,
                                                const float* __restrict__ bv,
                                                f16* __restrict__ xh,
                                                f16* __restrict__ WqkvT,
                                                f16* __restrict__ WoT,
                                                float* __restrict__ bqkv) {
  __shared__ f16 tile[64][65];
  const int bid = blockIdx.x;
  if (bid < 4096) {
    int i = bid * 256 + threadIdx.x;   // n4 = 4096*256 exactly
    float4 v = ((const float4*)x)[i];
    f16x4 o;
    o[0] = (f16)v.x; o[1] = (f16)v.y; o[2] = (f16)v.z; o[3] = (f16)v.w;
    *(f16x4*)(xh + (size_t)i * 4) = o;
  } else if (bid < 5120) {
    int t = bid - 4096;
    int z = t >> 8, rem = t & 255;
    const float* W = (z == 0) ? Wq : (z == 1) ? Wk : (z == 2) ? Wv : Wo;
    f16* Wt = (z < 3) ? (WqkvT + (size_t)z * H * H) : WoT;
    const float scale = (z == 0) ? QSCALE : 1.0f;
    int k0 = (rem >> 4) * 64, n0 = (rem & 15) * 64;
    for (int p = 0; p < 16; ++p) {
      int idx = threadIdx.x + p * 256;
      int r = idx >> 6, c = idx & 63;
      tile[r][c] = (f16)(W[(size_t)(k0 + r) * H + n0 + c] * scale);
    }
    __syncthreads();
    for (int p = 0; p < 16; ++p) {
      int idx = threadIdx.x + p * 256;
      int r = idx >> 6, c = idx & 63;
      Wt[(size_t)(n0 + r) * H + k0 + c] = tile[c][r];
    }
  } else {
    int i = (bid - 5120) * 256 + threadIdx.x;
    if (i < 3072) {
      float v = (i < 1024) ? bq[i] * QSCALE : ((i < 2048) ? bk[i - 1024] : bv[i - 2048]);
      bqkv[i] = v;
    }
  }
}

// LDS tiles for GEMM/K: rows of 64 f16 = 8 granules of 16B; slot s of row r
// holds granule s^(r&7) (self-inverse XOR swizzle, conflict-free b128 reads).
__device__ __forceinline__ f16x8 lds_frag(const f16* base, int row, int gr) {
  return *(const f16x8*)(base + row * 64 + ((gr ^ (row & 7)) << 3));
}

// ---------- GEMM: C[M][N] = A[M][K] @ Bt[N][K]^T + bias[n] ----------
template <int TM, int TN, bool OUT_F32>
__global__ __launch_bounds__(256) void gemm_f16_bt(const f16* __restrict__ A,
                                                   const f16* __restrict__ Bt,
                                                   const float* __restrict__ bias,
                                                   void* __restrict__ Cout,
                                                   int Nn, int Kk) {
  __shared__ f16 As[TM * 64];
  __shared__ f16 Bs[TN * 64];
  const int tid = threadIdx.x;
  const int lane = tid & 63, w = tid >> 6;
  const int quad = lane >> 4, l16 = lane & 15;
  const int wm = w >> 1, wn = w & 1;
  const int m0 = blockIdx.y * TM, n0 = blockIdx.x * TN;
  constexpr int AM = TM / 32, AN = TN / 32;

  f32x4 acc[AM][AN];
  for (int a = 0; a < AM; ++a)
    for (int b2 = 0; b2 < AN; ++b2)
      for (int r = 0; r < 4; ++r) acc[a][b2][r] = 0.f;

  for (int k0 = 0; k0 < Kk; k0 += 64) {
    for (int p = 0; p < TM * 8 / 256; ++p) {
      int slot = p * 256 + w * 64 + lane;
      int r = slot >> 3, g = (slot & 7) ^ (r & 7);
      gload_lds16(A + (size_t)(m0 + r) * Kk + k0 + g * 8,
                  (char*)As + (p * 256 + w * 64) * 16);
    }
    for (int p = 0; p < TN * 8 / 256; ++p) {
      int slot = p * 256 + w * 64 + lane;
      int r = slot >> 3, g = (slot & 7) ^ (r & 7);
      gload_lds16(Bt + (size_t)(n0 + r) * Kk + k0 + g * 8,
                  (char*)Bs + (p * 256 + w * 64) * 16);
    }
    __syncthreads();
    for (int ks = 0; ks < 2; ++ks) {
      f16x8 af[AM], bf[AN];
      for (int t = 0; t < AM; ++t)
        af[t] = lds_frag(As, wm * (TM / 2) + t * 16 + l16, ks * 4 + quad);
      for (int t = 0; t < AN; ++t)
        bf[t] = lds_frag(Bs, wn * (TN / 2) + t * 16 + l16, ks * 4 + quad);
      for (int tm = 0; tm < AM; ++tm)
        for (int tn = 0; tn < AN; ++tn)
          acc[tm][tn] = MFMA32(af[tm], bf[tn], acc[tm][tn]);
    }
    __syncthreads();
  }

  for (int tm = 0; tm < AM; ++tm)
    for (int tn = 0; tn < AN; ++tn)
      for (int r = 0; r < 4; ++r) {
        int m = m0 + wm * (TM / 2) + tm * 16 + quad * 4 + r;
        int n = n0 + wn * (TN / 2) + tn * 16 + l16;
        float v = acc[tm][tn][r] + bias[n];
        if (OUT_F32)
          ((float*)Cout)[(size_t)m * Nn + n] = v;
        else
          ((f16*)Cout)[(size_t)m * Nn + n] = (f16)v;
      }
}

// ---------- flash attention v5: 64 q per wave (LDS reads amortized 4x) ----------
// S^T = K.Q^T (16x16x32), P = 2^S in-lane, PV via 16x16x16 MFMA (B-layout ==
// QK C-layout). Block: 4 waves x 64 q = 256 q; kv tile 128, double-buffered.
// Grid (T/256, NH, B) = 256 blocks = 1/CU. Each kf/vf LDS fragment read now
// feeds 4 MFMAs (tq=0..3) -- per-work LDS pipe cost halves vs v4.

__global__ __launch_bounds__(256, 1) void attn_fused(const f16* __restrict__ QKV,
                                                     const int* __restrict__ mask,
                                                     f16* __restrict__ ctx) {
  __shared__ f16 Kt[2][128 * 64];  // [kv][d], XOR-granule swizzle
  __shared__ f16 Vt[2][80 * 128];  // [d*128 + (kv+4*(d&15))%128]; row 64 = mask

  const int tid = threadIdx.x;
  const int w = tid >> 6, lane = tid & 63;
  const int quad = lane >> 4, l16 = lane & 15;
  const int q0 = blockIdx.x * 256, h = blockIdx.y, b = blockIdx.z;

  const int vkv = tid & 127;          // kv row this thread stages for V
  const int vgb = (tid >> 7) * 4;     // granule base (0 or 4)
  const size_t kbase = (size_t)(b * T) * NQKV + H + h * HD;
  const size_t vbase = (size_t)(b * T) * NQKV + 2 * H + h * HD;

  // Q B-frags (B[k=d=quad*8+j][n=q=l16]); scale folded into Wq/bq
  f16x8 qf[4][2];
  for (int tq = 0; tq < 4; ++tq) {
    const f16* qrow = QKV + (size_t)(b * T + q0 + w * 64 + tq * 16 + l16) * NQKV + h * HD;
    qf[tq][0] = *(const f16x8*)(qrow + quad * 8);
    qf[tq][1] = *(const f16x8*)(qrow + 32 + quad * 8);
  }

  f32x4 oacc[4][5];
  for (int tq = 0; tq < 4; ++tq)
    for (int t = 0; t < 5; ++t)
      for (int r = 0; r < 4; ++r) oacc[tq][t][r] = 0.f;

  // ---- prologue: stage tile 0 into buffer 0 ----
  for (int p = 0; p < 4; ++p) {
    int slot = p * 256 + w * 64 + lane;
    int r = slot >> 3, g = (slot & 7) ^ (r & 7);
    gload_lds16(QKV + kbase + (size_t)r * NQKV + g * 8,
                (char*)&Kt[0][0] + (p * 256 + w * 64) * 16);
  }
  {
    f16 vm = (f16)(float)(mask[b * T + vkv] != 0);
    const f16* vrow = QKV + vbase + (size_t)vkv * NQKV;
    for (int p = 0; p < 4; ++p) {
      int g = vgb + p;
      f16x8 v = *(const f16x8*)(vrow + g * 8);
      for (int j = 0; j < 8; ++j) {
        int d = g * 8 + j;
        Vt[0][d * 128 + ((vkv + 4 * (d & 15)) & 127)] = v[j] * vm;
      }
    }
    if (tid < 128) Vt[0][64 * 128 + vkv] = vm;
  }
  __syncthreads();

  for (int it = 0; it < T / 128; ++it) {
    const int cur = it & 1, nxt = cur ^ 1;
    const int kvn = (it + 1) * 128;
    const bool pf = kvn < T;

    // ---- issue next tile's loads first (latency hidden by compute) ----
    f16x8 vreg[4] = {};
    f16 vm = (f16)0;
    if (pf) {
      for (int p = 0; p < 4; ++p) {
        int slot = p * 256 + w * 64 + lane;
        int r = slot >> 3, g = (slot & 7) ^ (r & 7);
        gload_lds16(QKV + kbase + (size_t)(kvn + r) * NQKV + g * 8,
                    (char*)&Kt[nxt][0] + (p * 256 + w * 64) * 16);
      }
      vm = (f16)(float)(mask[b * T + kvn + vkv] != 0);
      const f16* vrow = QKV + vbase + (size_t)(kvn + vkv) * NQKV;
      for (int p = 0; p < 4; ++p)
        vreg[p] = *(const f16x8*)(vrow + (vgb + p) * 8);
    }

    // ---- compute on current buffer ----
    const f16* Kc = &Kt[cur][0];
    const f16* Vc = &Vt[cur][0];
    for (int tk = 0; tk < 8; ++tk) {
      f16x8 kf0 = lds_frag(Kc, tk * 16 + l16, quad);
      f16x8 kf1 = lds_frag(Kc, tk * 16 + l16, 4 + quad);
      f16x4 vf[5];
      for (int td = 0; td < 5; ++td)
        vf[td] = *(const f16x4*)&Vc[(td * 16 + l16) * 128 +
                                    ((tk * 16 + quad * 4 + 4 * l16) & 127)];
      for (int tq = 0; tq < 4; ++tq) {
        f32x4 s = {0.f, 0.f, 0.f, 0.f};
        s = MFMA32(kf0, qf[tq][0], s);
        s = MFMA32(kf1, qf[tq][1], s);
        h16x2 p01 = __builtin_amdgcn_cvt_pkrtz(__builtin_amdgcn_exp2f(s[0]),
                                               __builtin_amdgcn_exp2f(s[1]));
        h16x2 p23 = __builtin_amdgcn_cvt_pkrtz(__builtin_amdgcn_exp2f(s[2]),
                                               __builtin_amdgcn_exp2f(s[3]));
        f16x4 pfr;
        pfr[0] = (f16)p01[0]; pfr[1] = (f16)p01[1];
        pfr[2] = (f16)p23[0]; pfr[3] = (f16)p23[1];
        for (int td = 0; td < 5; ++td)
          oacc[tq][td] = MFMA16(vf[td], pfr, oacc[tq][td]);
      }
    }

    // ---- scatter next V tile into LDS ----
    if (pf) {
      for (int p = 0; p < 4; ++p) {
        int g = vgb + p;
        for (int j = 0; j < 8; ++j) {
          int d = g * 8 + j;
          Vt[nxt][d * 128 + (((kvn + vkv) + 4 * (d & 15)) & 127)] = vreg[p][j] * vm;
        }
      }
      if (tid < 128) Vt[nxt][64 * 128 + vkv] = vm;
      __syncthreads();
    }
  }

  // epilogue: l[q] = O^T[64][q] (tile 4 reg 0 on quad-0 lanes)
  for (int tq = 0; tq < 4; ++tq) {
    float lq = __shfl(oacc[tq][4][0], l16, 64);
    float inv = 1.f / lq;
    int row = b * T + q0 + w * 64 + tq * 16 + l16;
    for (int td = 0; td < 4; ++td) {
      f16x4 o;
      for (int r = 0; r < 4; ++r) o[r] = (f16)(oacc[tq][td][r] * inv);
      *(f16x4*)(ctx + (size_t)row * H + h * HD + td * 16 + quad * 4) = o;
    }
  }
}

// ---------- launch ----------

extern "C" void kernel_launch(void* const* d_in, const int* in_sizes, int n_in,
                              void* d_out, int out_size, void* d_ws, size_t ws_size,
                              hipStream_t stream) {
  const float* x  = (const float*)d_in[0];
  const int* mask = (const int*)d_in[1];
  const float* Wq = (const float*)d_in[2];
  const float* bq = (const float*)d_in[3];
  const float* Wk = (const float*)d_in[4];
  const float* bk = (const float*)d_in[5];
  const float* Wv = (const float*)d_in[6];
  const float* bv = (const float*)d_in[7];
  const float* Wo = (const float*)d_in[8];
  const float* bo = (const float*)d_in[9];
  float* out = (float*)d_out;

  char* ws = (char*)d_ws;
  f16* xh      = (f16*)(ws);                       // 8 MB  [4096][1024]
  f16* Wqkv_t  = (f16*)(ws + (8u  << 20));         // 6 MB  [3072][1024]
  f16* Wot     = (f16*)(ws + (14u << 20));         // 2 MB  [1024][1024]
  float* bqkv  = (float*)(ws + (16u << 20));       // 12 KB [3072]
  f16* QKV     = (f16*)(ws + (17u << 20));         // 24 MB [4096][3072]
  f16* ctx     = (f16*)(ws + (42u << 20));         // 8 MB  [4096][1024]

  pack_all<<<dim3(5132), 256, 0, stream>>>(x, Wq, Wk, Wv, Wo, bq, bk, bv,
                                           xh, Wqkv_t, Wot, bqkv);

  gemm_f16_bt<128, 128, false><<<dim3(NQKV / 128, M / 128), 256, 0, stream>>>(
      xh, Wqkv_t, bqkv, QKV, NQKV, H);

  attn_fused<<<dim3(T / 256, NH, Bb), 256, 0, stream>>>(QKV, mask, ctx);

  gemm_f16_bt<128, 64, true><<<dim3(H / 64, M / 128), 256, 0, stream>>>(
      ctx, Wot, bo, out, H, H);
}

// Round 7
// 210.106 us; speedup vs baseline: 1.0566x; 1.0566x over previous
//
#include <hip/hip_runtime.h>

typedef _Float16 f16;
typedef _Float16 f16x8 __attribute__((ext_vector_type(8)));
typedef _Float16 f16x4 __attribute__((ext_vector_type(4)));
typedef __fp16 h16x2 __attribute__((ext_vector_type(2)));
typedef float f32x4 __attribute__((ext_vector_type(4)));

#define MFMA32(a, b, c) __builtin_amdgcn_mfma_f32_16x16x32_f16((a), (b), (c), 0, 0, 0)
#define MFMA16(a, b, c) __builtin_amdgcn_mfma_f32_16x16x16f16((a), (b), (c), 0, 0, 0)

static constexpr int Bb = 2, T = 2048, H = 1024, NH = 16, HD = 64;
static constexpr int M = Bb * T;      // 4096 rows
static constexpr int NQKV = 3 * H;    // 3072
// fold 1/sqrt(64) * log2(e) into Wq/bq so P = 2^S via raw v_exp_f32
#define QSCALE 0.1803368801111f

// async global->LDS, 16B per lane; LDS dest = wave-uniform base + lane*16
__device__ __forceinline__ void gload_lds16(const void* g, void* l) {
  __builtin_amdgcn_global_load_lds(
      (const __attribute__((address_space(1))) void*)g,
      (__attribute__((address_space(3))) void*)l, 16, 0, 0);
}

// ---------- fused pack kernel ----------
// blocks [0,4096): x f32->f16; [4096,5120): 4 weight transposes; [5120,5132): bias
__global__ __launch_bounds__(256) void pack_all(const float* __restrict__ x,
                                                const float* __restrict__ Wq,
                                                const float* __restrict__ Wk,
                                                const float* __restrict__ Wv,
                                                const float* __restrict__ Wo,
                                                const float* __restrict__ bq,
                                                const float* __restrict__ bk,
                                                const float* __restrict__ bv,
                                                f16* __restrict__ xh,
                                                f16* __restrict__ WqkvT,
                                                f16* __restrict__ WoT,
                                                float* __restrict__ bqkv) {
  __shared__ f16 tile[64][65];
  const int bid = blockIdx.x;
  if (bid < 4096) {
    int i = bid * 256 + threadIdx.x;   // n4 = 4096*256 exactly
    float4 v = ((const float4*)x)[i];
    f16x4 o;
    o[0] = (f16)v.x; o[1] = (f16)v.y; o[2] = (f16)v.z; o[3] = (f16)v.w;
    *(f16x4*)(xh + (size_t)i * 4) = o;
  } else if (bid < 5120) {
    int t = bid - 4096;
    int z = t >> 8, rem = t & 255;
    const float* W = (z == 0) ? Wq : (z == 1) ? Wk : (z == 2) ? Wv : Wo;
    f16* Wt = (z < 3) ? (WqkvT + (size_t)z * H * H) : WoT;
    const float scale = (z == 0) ? QSCALE : 1.0f;
    int k0 = (rem >> 4) * 64, n0 = (rem & 15) * 64;
    for (int p = 0; p < 16; ++p) {
      int idx = threadIdx.x + p * 256;
      int r = idx >> 6, c = idx & 63;
      tile[r][c] = (f16)(W[(size_t)(k0 + r) * H + n0 + c] * scale);
    }
    __syncthreads();
    for (int p = 0; p < 16; ++p) {
      int idx = threadIdx.x + p * 256;
      int r = idx >> 6, c = idx & 63;
      Wt[(size_t)(n0 + r) * H + k0 + c] = tile[c][r];
    }
  } else {
    int i = (bid - 5120) * 256 + threadIdx.x;
    if (i < 3072) {
      float v = (i < 1024) ? bq[i] * QSCALE : ((i < 2048) ? bk[i - 1024] : bv[i - 2048]);
      bqkv[i] = v;
    }
  }
}

// LDS tiles for GEMM/K: rows of 64 f16 = 8 granules of 16B; slot s of row r
// holds granule s^(r&7) (self-inverse XOR swizzle, conflict-free b128 reads).
__device__ __forceinline__ f16x8 lds_frag(const f16* base, int row, int gr) {
  return *(const f16x8*)(base + row * 64 + ((gr ^ (row & 7)) << 3));
}

// ---------- GEMM: C[M][N] = A[M][K] @ Bt[N][K]^T + bias[n] ----------
template <int TM, int TN, bool OUT_F32>
__global__ __launch_bounds__(256) void gemm_f16_bt(const f16* __restrict__ A,
                                                   const f16* __restrict__ Bt,
                                                   const float* __restrict__ bias,
                                                   void* __restrict__ Cout,
                                                   int Nn, int Kk) {
  __shared__ f16 As[TM * 64];
  __shared__ f16 Bs[TN * 64];
  const int tid = threadIdx.x;
  const int lane = tid & 63, w = tid >> 6;
  const int quad = lane >> 4, l16 = lane & 15;
  const int wm = w >> 1, wn = w & 1;
  const int m0 = blockIdx.y * TM, n0 = blockIdx.x * TN;
  constexpr int AM = TM / 32, AN = TN / 32;

  f32x4 acc[AM][AN];
  for (int a = 0; a < AM; ++a)
    for (int b2 = 0; b2 < AN; ++b2)
      for (int r = 0; r < 4; ++r) acc[a][b2][r] = 0.f;

  for (int k0 = 0; k0 < Kk; k0 += 64) {
    for (int p = 0; p < TM * 8 / 256; ++p) {
      int slot = p * 256 + w * 64 + lane;
      int r = slot >> 3, g = (slot & 7) ^ (r & 7);
      gload_lds16(A + (size_t)(m0 + r) * Kk + k0 + g * 8,
                  (char*)As + (p * 256 + w * 64) * 16);
    }
    for (int p = 0; p < TN * 8 / 256; ++p) {
      int slot = p * 256 + w * 64 + lane;
      int r = slot >> 3, g = (slot & 7) ^ (r & 7);
      gload_lds16(Bt + (size_t)(n0 + r) * Kk + k0 + g * 8,
                  (char*)Bs + (p * 256 + w * 64) * 16);
    }
    __syncthreads();
    for (int ks = 0; ks < 2; ++ks) {
      f16x8 af[AM], bf[AN];
      for (int t = 0; t < AM; ++t)
        af[t] = lds_frag(As, wm * (TM / 2) + t * 16 + l16, ks * 4 + quad);
      for (int t = 0; t < AN; ++t)
        bf[t] = lds_frag(Bs, wn * (TN / 2) + t * 16 + l16, ks * 4 + quad);
      for (int tm = 0; tm < AM; ++tm)
        for (int tn = 0; tn < AN; ++tn)
          acc[tm][tn] = MFMA32(af[tm], bf[tn], acc[tm][tn]);
    }
    __syncthreads();
  }

  for (int tm = 0; tm < AM; ++tm)
    for (int tn = 0; tn < AN; ++tn)
      for (int r = 0; r < 4; ++r) {
        int m = m0 + wm * (TM / 2) + tm * 16 + quad * 4 + r;
        int n = n0 + wn * (TN / 2) + tn * 16 + l16;
        float v = acc[tm][tn][r] + bias[n];
        if (OUT_F32)
          ((float*)Cout)[(size_t)m * Nn + n] = v;
        else
          ((f16*)Cout)[(size_t)m * Nn + n] = (f16)v;
      }
}

// ---------- flash attention v6: kv-split wave groups ----------
// Block = 512 threads (8 waves), 256 q rows, kv tile 256 (double-buffered).
// Waves 0-3 (group 0) process the tile's first 128 kv, waves 4-7 (group 1)
// the second 128 kv, for the SAME 256 q. P = 2^S has no running max, so the
// groups' O^T/l partials are purely additive -> f32 combine via LDS at the
// end. 64 q per wave (tq=0..3) amortizes every K/V LDS fragment over 4 MFMAs
// while keeping 8 waves/CU = 2/SIMD for latency hiding.
// Grid (T/256, NH, B) = 256 blocks = 1/CU. LDS = 130 KB (of 160).

static constexpr int KT_ELE = 256 * 64;   // one Kt buffer
static constexpr int VT_ELE = 66 * 256;   // one Vt buffer (row 64 = mask)

__global__ __launch_bounds__(512, 1) void attn_fused(const f16* __restrict__ QKV,
                                                     const int* __restrict__ mask,
                                                     f16* __restrict__ ctx) {
  __shared__ char smem[(2 * KT_ELE + 2 * VT_ELE) * 2];  // 133,120 B
  f16* KtB = (f16*)smem;                       // [2][256*64], [kv][d] swizzled
  f16* VtB = (f16*)(smem + 2 * KT_ELE * 2);    // [2][66*256], [d][kv] rotated
  float* cmb = (float*)smem;                   // combine region (epilogue)

  const int tid = threadIdx.x;
  const int w = tid >> 6, lane = tid & 63;
  const int quad = lane >> 4, l16 = lane & 15;
  const int g = w >> 2, wq = w & 3;            // kv-group, q-wave within group
  const int q0 = blockIdx.x * 256, h = blockIdx.y, b = blockIdx.z;

  const int vkv = tid & 255;                   // kv row this thread stages for V
  const int vgb = (tid >> 8) * 4;              // granule base (0 or 4)
  const size_t kbase = (size_t)(b * T) * NQKV + H + h * HD;
  const size_t vbase = (size_t)(b * T) * NQKV + 2 * H + h * HD;

  // Q B-frags (B[k=d=quad*8+j][n=q=l16]); scale folded into Wq/bq
  f16x8 qf[4][2];
  for (int tq = 0; tq < 4; ++tq) {
    const f16* qrow = QKV + (size_t)(b * T + q0 + wq * 64 + tq * 16 + l16) * NQKV + h * HD;
    qf[tq][0] = *(const f16x8*)(qrow + quad * 8);
    qf[tq][1] = *(const f16x8*)(qrow + 32 + quad * 8);
  }

  f32x4 oacc[4][5];
  for (int tq = 0; tq < 4; ++tq)
    for (int t = 0; t < 5; ++t)
      for (int r = 0; r < 4; ++r) oacc[tq][t][r] = 0.f;

  // ---- prologue: stage 256-kv tile 0 into buffer 0 ----
  for (int p = 0; p < 4; ++p) {
    int slot = p * 512 + w * 64 + lane;        // 0..2047: 256 rows x 8 granules
    int r = slot >> 3, gs = (slot & 7) ^ (r & 7);
    gload_lds16(QKV + kbase + (size_t)r * NQKV + gs * 8,
                (char*)KtB + (p * 512 + w * 64) * 16);
  }
  {
    f16 vm = (f16)(float)(mask[b * T + vkv] != 0);
    const f16* vrow = QKV + vbase + (size_t)vkv * NQKV;
    for (int p = 0; p < 4; ++p) {
      int gr = vgb + p;
      f16x8 v = *(const f16x8*)(vrow + gr * 8);
      for (int j = 0; j < 8; ++j) {
        int d = gr * 8 + j;
        VtB[d * 256 + ((vkv + 4 * (d & 15)) & 255)] = v[j] * vm;
      }
    }
    if (tid < 256) VtB[64 * 256 + vkv] = vm;   // mask row (rotation 0)
  }
  __syncthreads();

  for (int it = 0; it < T / 256; ++it) {
    const int cur = it & 1, nxt = cur ^ 1;
    const int kvn = (it + 1) * 256;
    const bool pf = kvn < T;

    // ---- issue next tile's loads first (latency hidden by compute) ----
    f16x8 vreg[4] = {};
    f16 vm = (f16)0;
    if (pf) {
      for (int p = 0; p < 4; ++p) {
        int slot = p * 512 + w * 64 + lane;
        int r = slot >> 3, gs = (slot & 7) ^ (r & 7);
        gload_lds16(QKV + kbase + (size_t)(kvn + r) * NQKV + gs * 8,
                    (char*)(KtB + nxt * KT_ELE) + (p * 512 + w * 64) * 16);
      }
      vm = (f16)(float)(mask[b * T + kvn + vkv] != 0);
      const f16* vrow = QKV + vbase + (size_t)(kvn + vkv) * NQKV;
      for (int p = 0; p < 4; ++p)
        vreg[p] = *(const f16x8*)(vrow + (vgb + p) * 8);
    }

    // ---- compute on current buffer; group g takes kv half g*128 ----
    const f16* Kc = KtB + cur * KT_ELE;
    const f16* Vc = VtB + cur * VT_ELE;
    for (int tk = 0; tk < 8; ++tk) {
      f16x8 kf0 = lds_frag(Kc, g * 128 + tk * 16 + l16, quad);
      f16x8 kf1 = lds_frag(Kc, g * 128 + tk * 16 + l16, 4 + quad);
      f16x4 vf[5];
      for (int td = 0; td < 5; ++td)
        vf[td] = *(const f16x4*)&Vc[(td * 16 + l16) * 256 +
                                    ((g * 128 + tk * 16 + quad * 4 + 4 * l16) & 255)];
      for (int tq = 0; tq < 4; ++tq) {
        f32x4 s = {0.f, 0.f, 0.f, 0.f};
        s = MFMA32(kf0, qf[tq][0], s);
        s = MFMA32(kf1, qf[tq][1], s);
        h16x2 p01 = __builtin_amdgcn_cvt_pkrtz(__builtin_amdgcn_exp2f(s[0]),
                                               __builtin_amdgcn_exp2f(s[1]));
        h16x2 p23 = __builtin_amdgcn_cvt_pkrtz(__builtin_amdgcn_exp2f(s[2]),
                                               __builtin_amdgcn_exp2f(s[3]));
        f16x4 pfr;
        pfr[0] = (f16)p01[0]; pfr[1] = (f16)p01[1];
        pfr[2] = (f16)p23[0]; pfr[3] = (f16)p23[1];
        for (int td = 0; td < 5; ++td)
          oacc[tq][td] = MFMA16(vf[td], pfr, oacc[tq][td]);
      }
    }

    // ---- scatter next V tile into LDS ----
    if (pf) {
      f16* Vn = VtB + nxt * VT_ELE;
      for (int p = 0; p < 4; ++p) {
        int gr = vgb + p;
        for (int j = 0; j < 8; ++j) {
          int d = gr * 8 + j;
          Vn[d * 256 + ((vkv + 4 * (d & 15)) & 255)] = vreg[p][j] * vm;
        }
      }
      if (tid < 256) Vn[64 * 256 + vkv] = vm;
      __syncthreads();
    }
  }

  // ---- combine group partials (purely additive; f32 via LDS, stride 81) ----
  __syncthreads();  // all tile reads done; LDS free for reuse
  if (g == 1) {
    float* dst = cmb + ((size_t)(wq * 64 + lane)) * 81;
    for (int tq = 0; tq < 4; ++tq)
      for (int td = 0; td < 5; ++td)
        for (int r = 0; r < 4; ++r) dst[(tq * 5 + td) * 4 + r] = oacc[tq][td][r];
  }
  __syncthreads();
  if (g == 0) {
    const float* src = cmb + ((size_t)(wq * 64 + lane)) * 81;
    for (int tq = 0; tq < 4; ++tq)
      for (int td = 0; td < 5; ++td)
        for (int r = 0; r < 4; ++r) oacc[tq][td][r] += src[(tq * 5 + td) * 4 + r];

    // epilogue: l[q] = O^T[64][q] (tile 4 reg 0 on quad-0 lanes)
    for (int tq = 0; tq < 4; ++tq) {
      float lq = __shfl(oacc[tq][4][0], l16, 64);
      float inv = 1.f / lq;
      int row = b * T + q0 + wq * 64 + tq * 16 + l16;
      for (int td = 0; td < 4; ++td) {
        f16x4 o;
        for (int r = 0; r < 4; ++r) o[r] = (f16)(oacc[tq][td][r] * inv);
        *(f16x4*)(ctx + (size_t)row * H + h * HD + td * 16 + quad * 4) = o;
      }
    }
  }
}

// ---------- launch ----------

extern "C" void kernel_launch(void* const* d_in, const int* in_sizes, int n_in,
                              void* d_out, int out_size, void* d_ws, size_t ws_size,
                              hipStream_t stream) {
  const float* x  = (const float*)d_in[0];
  const int* mask = (const int*)d_in[1];
  const float* Wq = (const float*)d_in[2];
  const float* bq = (const float*)d_in[3];
  const float* Wk = (const float*)d_in[4];
  const float* bk = (const float*)d_in[5];
  const float* Wv = (const float*)d_in[6];
  const float* bv = (const float*)d_in[7];
  const float* Wo = (const float*)d_in[8];
  const float* bo = (const float*)d_in[9];
  float* out = (float*)d_out;

  char* ws = (char*)d_ws;
  f16* xh      = (f16*)(ws);                       // 8 MB  [4096][1024]
  f16* Wqkv_t  = (f16*)(ws + (8u  << 20));         // 6 MB  [3072][1024]
  f16* Wot     = (f16*)(ws + (14u << 20));         // 2 MB  [1024][1024]
  float* bqkv  = (float*)(ws + (16u << 20));       // 12 KB [3072]
  f16* QKV     = (f16*)(ws + (17u << 20));         // 24 MB [4096][3072]
  f16* ctx     = (f16*)(ws + (42u << 20));         // 8 MB  [4096][1024]

  pack_all<<<dim3(5132), 256, 0, stream>>>(x, Wq, Wk, Wv, Wo, bq, bk, bv,
                                           xh, Wqkv_t, Wot, bqkv);

  gemm_f16_bt<128, 128, false><<<dim3(NQKV / 128, M / 128), 256, 0, stream>>>(
      xh, Wqkv_t, bqkv, QKV, NQKV, H);

  attn_fused<<<dim3(T / 256, NH, Bb), 512, 0, stream>>>(QKV, mask, ctx);

  gemm_f16_bt<128, 64, true><<<dim3(H / 64, M / 128), 256, 0, stream>>>(
      ctx, Wot, bo, out, H, H);
}

// Round 8
// 209.879 us; speedup vs baseline: 1.0578x; 1.0011x over previous
//
#include <hip/hip_runtime.h>

typedef _Float16 f16;
typedef _Float16 f16x8 __attribute__((ext_vector_type(8)));
typedef _Float16 f16x4 __attribute__((ext_vector_type(4)));
typedef __fp16 h16x2 __attribute__((ext_vector_type(2)));
typedef float f32x4 __attribute__((ext_vector_type(4)));

#define MFMA32(a, b, c) __builtin_amdgcn_mfma_f32_16x16x32_f16((a), (b), (c), 0, 0, 0)

static constexpr int Bb = 2, T = 2048, H = 1024, NH = 16, HD = 64;
static constexpr int M = Bb * T;      // 4096 rows
static constexpr int NQKV = 3 * H;    // 3072
// fold 1/sqrt(64) * log2(e) into Wq/bq so P = 2^S via raw v_exp_f32
#define QSCALE 0.1803368801111f

__device__ __forceinline__ void gload_lds16(const void* g, void* l) {
  __builtin_amdgcn_global_load_lds(
      (const __attribute__((address_space(1))) void*)g,
      (__attribute__((address_space(3))) void*)l, 16, 0, 0);
}

// ---------- fused pack kernel ----------
// [0,4096): x f32->f16; [4096,5120): weight transposes; [5120,5132): bias;
// [5132,5164): mask -> f32
__global__ __launch_bounds__(256) void pack_all(const float* __restrict__ x,
                                                const float* __restrict__ Wq,
                                                const float* __restrict__ Wk,
                                                const float* __restrict__ Wv,
                                                const float* __restrict__ Wo,
                                                const float* __restrict__ bq,
                                                const float* __restrict__ bk,
                                                const float* __restrict__ bv,
                                                const int* __restrict__ mask,
                                                f16* __restrict__ xh,
                                                f16* __restrict__ WqkvT,
                                                f16* __restrict__ WoT,
                                                float* __restrict__ bqkv,
                                                float* __restrict__ maskf) {
  __shared__ f16 tile[64][65];
  const int bid = blockIdx.x;
  if (bid < 4096) {
    int i = bid * 256 + threadIdx.x;
    float4 v = ((const float4*)x)[i];
    f16x4 o;
    o[0] = (f16)v.x; o[1] = (f16)v.y; o[2] = (f16)v.z; o[3] = (f16)v.w;
    *(f16x4*)(xh + (size_t)i * 4) = o;
  } else if (bid < 5120) {
    int t = bid - 4096;
    int z = t >> 8, rem = t & 255;
    const float* W = (z == 0) ? Wq : (z == 1) ? Wk : (z == 2) ? Wv : Wo;
    f16* Wt = (z < 3) ? (WqkvT + (size_t)z * H * H) : WoT;
    const float scale = (z == 0) ? QSCALE : 1.0f;
    int k0 = (rem >> 4) * 64, n0 = (rem & 15) * 64;
    for (int p = 0; p < 16; ++p) {
      int idx = threadIdx.x + p * 256;
      int r = idx >> 6, c = idx & 63;
      tile[r][c] = (f16)(W[(size_t)(k0 + r) * H + n0 + c] * scale);
    }
    __syncthreads();
    for (int p = 0; p < 16; ++p) {
      int idx = threadIdx.x + p * 256;
      int r = idx >> 6, c = idx & 63;
      Wt[(size_t)(n0 + r) * H + k0 + c] = tile[c][r];
    }
  } else if (bid < 5132) {
    int i = (bid - 5120) * 256 + threadIdx.x;
    if (i < 3072) {
      float v = (i < 1024) ? bq[i] * QSCALE : ((i < 2048) ? bk[i - 1024] : bv[i - 2048]);
      bqkv[i] = v;
    }
  } else {
    int i = (bid - 5132) * 256 + threadIdx.x;
    if (i < Bb * T) maskf[i] = mask[i] ? 1.0f : 0.0f;
  }
}

// ---------- V transpose: QKV V-part [kv][d] -> VT [b][h][d][T] ----------
// 64x64 tiles; LDS rotation (column-granule + row>>3) keeps b128 alignment
// and <=2-way banks both directions.
__global__ __launch_bounds__(256) void vtrans(const f16* __restrict__ QKV,
                                              f16* __restrict__ VT) {
  __shared__ f16 tile[64 * 64];
  const int tid = threadIdx.x;
  const int kv0 = blockIdx.x * 64, h = blockIdx.y, b = blockIdx.z;
  for (int p = 0; p < 2; ++p) {
    int idx = p * 256 + tid;
    int r = idx >> 3, gr = idx & 7;
    f16x8 v = *(const f16x8*)(QKV + (size_t)(b * T + kv0 + r) * NQKV + 2 * H + h * HD + gr * 8);
    *(f16x8*)&tile[r * 64 + (((gr + (r >> 3)) & 7) << 3)] = v;
  }
  __syncthreads();
  const size_t obase = ((size_t)(b * NH + h) * HD) * T + kv0;
  for (int p = 0; p < 2; ++p) {
    int idx = p * 256 + tid;
    int d = idx >> 3, kg = idx & 7;
    f16x8 v;
    for (int j = 0; j < 8; ++j) {
      int row = kg * 8 + j;
      v[j] = tile[row * 64 + ((((d >> 3) + kg) & 7) << 3) + (d & 7)];
    }
    *(f16x8*)(VT + obase + (size_t)d * T + kg * 8) = v;
  }
}

// LDS rows of 64 f16 = 8 granules; slot s of row r holds granule s^(r&7).
__device__ __forceinline__ f16x8 lds_frag(const f16* base, int row, int gr) {
  return *(const f16x8*)(base + row * 64 + ((gr ^ (row & 7)) << 3));
}

// ---------- GEMM: C[M][N] = A[M][K] @ Bt[N][K]^T + bias[n] ----------
template <int TM, int TN, bool OUT_F32>
__global__ __launch_bounds__(256) void gemm_f16_bt(const f16* __restrict__ A,
                                                   const f16* __restrict__ Bt,
                                                   const float* __restrict__ bias,
                                                   void* __restrict__ Cout,
                                                   int Nn, int Kk) {
  __shared__ f16 As[TM * 64];
  __shared__ f16 Bs[TN * 64];
  const int tid = threadIdx.x;
  const int lane = tid & 63, w = tid >> 6;
  const int quad = lane >> 4, l16 = lane & 15;
  const int wm = w >> 1, wn = w & 1;
  const int m0 = blockIdx.y * TM, n0 = blockIdx.x * TN;
  constexpr int AM = TM / 32, AN = TN / 32;

  f32x4 acc[AM][AN];
  for (int a = 0; a < AM; ++a)
    for (int b2 = 0; b2 < AN; ++b2)
      for (int r = 0; r < 4; ++r) acc[a][b2][r] = 0.f;

  for (int k0 = 0; k0 < Kk; k0 += 64) {
    for (int p = 0; p < TM * 8 / 256; ++p) {
      int slot = p * 256 + w * 64 + lane;
      int r = slot >> 3, g = (slot & 7) ^ (r & 7);
      gload_lds16(A + (size_t)(m0 + r) * Kk + k0 + g * 8,
                  (char*)As + (p * 256 + w * 64) * 16);
    }
    for (int p = 0; p < TN * 8 / 256; ++p) {
      int slot = p * 256 + w * 64 + lane;
      int r = slot >> 3, g = (slot & 7) ^ (r & 7);
      gload_lds16(Bt + (size_t)(n0 + r) * Kk + k0 + g * 8,
                  (char*)Bs + (p * 256 + w * 64) * 16);
    }
    __syncthreads();
    for (int ks = 0; ks < 2; ++ks) {
      f16x8 af[AM], bf[AN];
      for (int t = 0; t < AM; ++t)
        af[t] = lds_frag(As, wm * (TM / 2) + t * 16 + l16, ks * 4 + quad);
      for (int t = 0; t < AN; ++t)
        bf[t] = lds_frag(Bs, wn * (TN / 2) + t * 16 + l16, ks * 4 + quad);
      for (int tm = 0; tm < AM; ++tm)
        for (int tn = 0; tn < AN; ++tn)
          acc[tm][tn] = MFMA32(af[tm], bf[tn], acc[tm][tn]);
    }
    __syncthreads();
  }

  for (int tm = 0; tm < AM; ++tm)
    for (int tn = 0; tn < AN; ++tn)
      for (int r = 0; r < 4; ++r) {
        int m = m0 + wm * (TM / 2) + tm * 16 + quad * 4 + r;
        int n = n0 + wn * (TN / 2) + tn * 16 + l16;
        float v = acc[tm][tn][r] + bias[n];
        if (OUT_F32)
          ((float*)Cout)[(size_t)m * Nn + n] = v;
        else
          ((f16*)Cout)[(size_t)m * Nn + n] = (f16)v;
      }
}

// ---------- flash attention v7 ----------
// Block = 512 thr = 4 q-waves x 2 kv-groups; 128 q/block; kv tile 128 dbuf;
// grid (16,16,2)=512 blocks = 2/CU -> 16 waves/CU (4/SIMD).
// K staged with PERMUTED rows: LDS row R -> kv = (R&~31)|quad_t*8|AB*4|r, so
// the two QK^T C-tiles of each 32-kv block emit P^T directly in MFMA32
// B-operand layout (kv = quad*8+j) -- PV is plain 16x16x32, zero shuffles.
// V comes pre-transposed from global (async staging, no scatter). l = VALU
// row-sum of masked P (f32 fmac), quad-reduced at the end.

static constexpr int KT_ELE = 128 * 64;
static constexpr int VT_ELE = 64 * 128;

__global__ __launch_bounds__(512, 4) void attn_fused(const f16* __restrict__ QKV,
                                                     const f16* __restrict__ VT,
                                                     const float* __restrict__ maskf,
                                                     f16* __restrict__ ctx) {
  __shared__ char smem[(2 * KT_ELE + 2 * VT_ELE) * 2];  // 64 KB
  f16* KtB = (f16*)smem;
  f16* VtB = (f16*)(smem + 2 * KT_ELE * 2);

  const int tid = threadIdx.x;
  const int w = tid >> 6, lane = tid & 63;
  const int quad = lane >> 4, l16 = lane & 15;
  const int qw = w & 3, g = w >> 2;
  const int q0 = blockIdx.x * 128, h = blockIdx.y, b = blockIdx.z;

  const size_t kbase = (size_t)(b * T) * NQKV + H + h * HD;
  const size_t vtbase = ((size_t)(b * NH + h) * HD) * T;
  const float* maskp = maskf + b * T;

  // Q B-frags
  f16x8 qf[2][2];
  for (int tq = 0; tq < 2; ++tq) {
    const f16* qrow = QKV + (size_t)(b * T + q0 + qw * 32 + tq * 16 + l16) * NQKV + h * HD;
    qf[tq][0] = *(const f16x8*)(qrow + quad * 8);
    qf[tq][1] = *(const f16x8*)(qrow + 32 + quad * 8);
  }

  f32x4 oacc[2][4];
  float lsum[2] = {0.f, 0.f};
  for (int tq = 0; tq < 2; ++tq)
    for (int t = 0; t < 4; ++t)
      for (int r = 0; r < 4; ++r) oacc[tq][t][r] = 0.f;

  // staging helper indices (2 K slots + 2 V slots per thread per tile)
  // K slot s: R=s>>3 (LDS row), granule (s&7)^(R&7), kv = perm(R)
  // V slot s: d=s>>4, col-granule cg=s&15 at rotated pos; true kv = cg*8-8*(d&15)
  auto stage = [&](int kv0, int buf) {
    f16* Kd = KtB + buf * KT_ELE;
    f16* Vd = VtB + buf * VT_ELE;
    for (int p = 0; p < 2; ++p) {
      int s = p * 512 + tid;
      int R = s >> 3, sg = (s & 7) ^ (R & 7);
      int kv = (R & ~31) | ((R & 12) << 1) | ((R & 16) >> 2) | (R & 3);
      gload_lds16(QKV + kbase + (size_t)(kv0 + kv) * NQKV + sg * 8,
                  (char*)Kd + (p * 512 + w * 64) * 16);
    }
    for (int p = 0; p < 2; ++p) {
      int s = p * 512 + tid;
      int d = s >> 4, cg = s & 15;
      int kvl = (cg * 8 - 8 * (d & 15)) & 127;
      gload_lds16(VT + vtbase + (size_t)d * T + kv0 + kvl,
                  (char*)Vd + (p * 512 + w * 64) * 16);
    }
  };

  stage(0, 0);
  __syncthreads();

  for (int it = 0; it < T / 128; ++it) {
    const int cur = it & 1, nxt = cur ^ 1;
    if (it + 1 < T / 128) stage((it + 1) * 128, nxt);

    const f16* Kc = KtB + cur * KT_ELE;
    const f16* Vc = VtB + cur * VT_ELE;

    for (int s = 0; s < 2; ++s) {
      const int bi = g * 2 + s;               // 32-kv block index in tile
      const int kvabs = it * 128 + bi * 32;
      // mask (f32x8 per lane, kv = quad*8+j)
      float4 m0 = *(const float4*)(maskp + kvabs + quad * 8);
      float4 m1 = *(const float4*)(maskp + kvabs + quad * 8 + 4);
      // K frags: tiles A,B of this 32-kv block
      f16x8 kfA0 = lds_frag(Kc, bi * 32 + l16, quad);
      f16x8 kfA1 = lds_frag(Kc, bi * 32 + l16, 4 + quad);
      f16x8 kfB0 = lds_frag(Kc, bi * 32 + 16 + l16, quad);
      f16x8 kfB1 = lds_frag(Kc, bi * 32 + 16 + l16, 4 + quad);
      // V frags (shared across tq): b128, kv = quad*8+j
      f16x8 vf[4];
      for (int td = 0; td < 4; ++td)
        vf[td] = *(const f16x8*)&Vc[(td * 16 + l16) * 128 +
                                    ((bi * 32 + quad * 8 + 8 * l16) & 127)];
      for (int tq = 0; tq < 2; ++tq) {
        f32x4 sA = {0.f, 0.f, 0.f, 0.f}, sB = {0.f, 0.f, 0.f, 0.f};
        sA = MFMA32(kfA0, qf[tq][0], sA);
        sA = MFMA32(kfA1, qf[tq][1], sA);
        sB = MFMA32(kfB0, qf[tq][0], sB);
        sB = MFMA32(kfB1, qf[tq][1], sB);
        float pA0 = __builtin_amdgcn_exp2f(sA[0]) * m0.x;
        float pA1 = __builtin_amdgcn_exp2f(sA[1]) * m0.y;
        float pA2 = __builtin_amdgcn_exp2f(sA[2]) * m0.z;
        float pA3 = __builtin_amdgcn_exp2f(sA[3]) * m0.w;
        float pB0 = __builtin_amdgcn_exp2f(sB[0]) * m1.x;
        float pB1 = __builtin_amdgcn_exp2f(sB[1]) * m1.y;
        float pB2 = __builtin_amdgcn_exp2f(sB[2]) * m1.z;
        float pB3 = __builtin_amdgcn_exp2f(sB[3]) * m1.w;
        lsum[tq] += ((pA0 + pA1) + (pA2 + pA3)) + ((pB0 + pB1) + (pB2 + pB3));
        union PF { f16x8 v; h16x2 h[4]; } pf;
        pf.h[0] = __builtin_amdgcn_cvt_pkrtz(pA0, pA1);
        pf.h[1] = __builtin_amdgcn_cvt_pkrtz(pA2, pA3);
        pf.h[2] = __builtin_amdgcn_cvt_pkrtz(pB0, pB1);
        pf.h[3] = __builtin_amdgcn_cvt_pkrtz(pB2, pB3);
        for (int td = 0; td < 4; ++td)
          oacc[tq][td] = MFMA32(vf[td], pf.v, oacc[tq][td]);
      }
    }
    __syncthreads();
  }

  // ---- combine the 2 kv-groups (additive partials) ----
  float* cmb = (float*)smem;
  const int slot = qw * 64 + lane;
  if (g == 1) {
    float* dst = cmb + slot * 35;
    int i = 0;
    for (int tq = 0; tq < 2; ++tq)
      for (int td = 0; td < 4; ++td)
        for (int r = 0; r < 4; ++r) dst[i++] = oacc[tq][td][r];
    dst[32] = lsum[0];
    dst[33] = lsum[1];
  }
  __syncthreads();
  if (g == 0) {
    const float* src = cmb + slot * 35;
    int i = 0;
    for (int tq = 0; tq < 2; ++tq)
      for (int td = 0; td < 4; ++td)
        for (int r = 0; r < 4; ++r) oacc[tq][td][r] += src[i++];
    lsum[0] += src[32];
    lsum[1] += src[33];

    for (int tq = 0; tq < 2; ++tq) {
      float l = lsum[tq];
      l += __shfl_xor(l, 16, 64);
      l += __shfl_xor(l, 32, 64);
      float inv = 1.f / l;
      int row = b * T + q0 + qw * 32 + tq * 16 + l16;
      for (int td = 0; td < 4; ++td) {
        f16x4 o;
        for (int r = 0; r < 4; ++r) o[r] = (f16)(oacc[tq][td][r] * inv);
        *(f16x4*)(ctx + (size_t)row * H + h * HD + td * 16 + quad * 4) = o;
      }
    }
  }
}

// ---------- launch ----------

extern "C" void kernel_launch(void* const* d_in, const int* in_sizes, int n_in,
                              void* d_out, int out_size, void* d_ws, size_t ws_size,
                              hipStream_t stream) {
  const float* x  = (const float*)d_in[0];
  const int* mask = (const int*)d_in[1];
  const float* Wq = (const float*)d_in[2];
  const float* bq = (const float*)d_in[3];
  const float* Wk = (const float*)d_in[4];
  const float* bk = (const float*)d_in[5];
  const float* Wv = (const float*)d_in[6];
  const float* bv = (const float*)d_in[7];
  const float* Wo = (const float*)d_in[8];
  const float* bo = (const float*)d_in[9];
  float* out = (float*)d_out;

  char* ws = (char*)d_ws;
  f16* xh      = (f16*)(ws);                            // 8 MB
  f16* Wqkv_t  = (f16*)(ws + (8u  << 20));              // 6 MB
  f16* Wot     = (f16*)(ws + (14u << 20));              // 2 MB
  float* bqkv  = (float*)(ws + (16u << 20));            // 12 KB
  float* maskf = (float*)(ws + (16u << 20) + 65536);    // 16 KB
  f16* QKV     = (f16*)(ws + (17u << 20));              // 24 MB
  f16* ctx     = (f16*)(ws + (42u << 20));              // 8 MB
  f16* VTr     = (f16*)(ws + (50u << 20));              // 8.4 MB [B][NH][64][T]

  pack_all<<<dim3(5164), 256, 0, stream>>>(x, Wq, Wk, Wv, Wo, bq, bk, bv, mask,
                                           xh, Wqkv_t, Wot, bqkv, maskf);

  gemm_f16_bt<128, 128, false><<<dim3(NQKV / 128, M / 128), 256, 0, stream>>>(
      xh, Wqkv_t, bqkv, QKV, NQKV, H);

  vtrans<<<dim3(T / 64, NH, Bb), 256, 0, stream>>>(QKV, VTr);

  attn_fused<<<dim3(T / 128, NH, Bb), 512, 0, stream>>>(QKV, VTr, maskf, ctx);

  gemm_f16_bt<128, 64, true><<<dim3(H / 64, M / 128), 256, 0, stream>>>(
      ctx, Wot, bo, out, H, H);
}

// Round 9
// 195.850 us; speedup vs baseline: 1.1335x; 1.0716x over previous
//
#include <hip/hip_runtime.h>

typedef _Float16 f16;
typedef _Float16 f16x8 __attribute__((ext_vector_type(8)));
typedef _Float16 f16x4 __attribute__((ext_vector_type(4)));
typedef __fp16 h16x2 __attribute__((ext_vector_type(2)));
typedef float f32x4 __attribute__((ext_vector_type(4)));

#define MFMA32(a, b, c) __builtin_amdgcn_mfma_f32_16x16x32_f16((a), (b), (c), 0, 0, 0)

static constexpr int Bb = 2, T = 2048, H = 1024, NH = 16, HD = 64;
static constexpr int M = Bb * T;      // 4096 rows
static constexpr int NQKV = 3 * H;    // 3072
// fold 1/sqrt(64) * log2(e) into Wq/bq so P = 2^S via raw v_exp_f32
#define QSCALE 0.1803368801111f

__device__ __forceinline__ void gload_lds16(const void* g, void* l) {
  __builtin_amdgcn_global_load_lds(
      (const __attribute__((address_space(1))) void*)g,
      (__attribute__((address_space(3))) void*)l, 16, 0, 0);
}

// ---------- fused pack kernel ----------
__global__ __launch_bounds__(256) void pack_all(const float* __restrict__ x,
                                                const float* __restrict__ Wq,
                                                const float* __restrict__ Wk,
                                                const float* __restrict__ Wv,
                                                const float* __restrict__ Wo,
                                                const float* __restrict__ bq,
                                                const float* __restrict__ bk,
                                                const float* __restrict__ bv,
                                                const int* __restrict__ mask,
                                                f16* __restrict__ xh,
                                                f16* __restrict__ WqkvT,
                                                f16* __restrict__ WoT,
                                                float* __restrict__ bqkv,
                                                float* __restrict__ maskf) {
  __shared__ f16 tile[64][65];
  const int bid = blockIdx.x;
  if (bid < 4096) {
    int i = bid * 256 + threadIdx.x;
    float4 v = ((const float4*)x)[i];
    f16x4 o;
    o[0] = (f16)v.x; o[1] = (f16)v.y; o[2] = (f16)v.z; o[3] = (f16)v.w;
    *(f16x4*)(xh + (size_t)i * 4) = o;
  } else if (bid < 5120) {
    int t = bid - 4096;
    int z = t >> 8, rem = t & 255;
    const float* W = (z == 0) ? Wq : (z == 1) ? Wk : (z == 2) ? Wv : Wo;
    f16* Wt = (z < 3) ? (WqkvT + (size_t)z * H * H) : WoT;
    const float scale = (z == 0) ? QSCALE : 1.0f;
    int k0 = (rem >> 4) * 64, n0 = (rem & 15) * 64;
    for (int p = 0; p < 16; ++p) {
      int idx = threadIdx.x + p * 256;
      int r = idx >> 6, c = idx & 63;
      tile[r][c] = (f16)(W[(size_t)(k0 + r) * H + n0 + c] * scale);
    }
    __syncthreads();
    for (int p = 0; p < 16; ++p) {
      int idx = threadIdx.x + p * 256;
      int r = idx >> 6, c = idx & 63;
      Wt[(size_t)(n0 + r) * H + k0 + c] = tile[c][r];
    }
  } else if (bid < 5132) {
    int i = (bid - 5120) * 256 + threadIdx.x;
    if (i < 3072) {
      float v = (i < 1024) ? bq[i] * QSCALE : ((i < 2048) ? bk[i - 1024] : bv[i - 2048]);
      bqkv[i] = v;
    }
  } else {
    int i = (bid - 5132) * 256 + threadIdx.x;
    if (i < Bb * T) maskf[i] = mask[i] ? 1.0f : 0.0f;
  }
}

// ---------- V transpose: QKV V-part [kv][d] -> VT [b][h][d][c] ----------
// PRE-ROTATED columns: c = (kv & ~127) | ((kv + 8*(d&15)) & 127), so attention
// V staging is pure linear DMA and frag reads stay conflict-free.
__global__ __launch_bounds__(256) void vtrans(const f16* __restrict__ QKV,
                                              f16* __restrict__ VT) {
  __shared__ f16 tile[64 * 64];
  const int tid = threadIdx.x;
  const int kv0 = blockIdx.x * 64, h = blockIdx.y, b = blockIdx.z;
  for (int p = 0; p < 2; ++p) {
    int idx = p * 256 + tid;
    int r = idx >> 3, gr = idx & 7;
    f16x8 v = *(const f16x8*)(QKV + (size_t)(b * T + kv0 + r) * NQKV + 2 * H + h * HD + gr * 8);
    *(f16x8*)&tile[r * 64 + (((gr + (r >> 3)) & 7) << 3)] = v;
  }
  __syncthreads();
  const size_t obase = ((size_t)(b * NH + h) * HD) * T;
  for (int p = 0; p < 2; ++p) {
    int idx = p * 256 + tid;
    int d = idx >> 3, kg = idx & 7;
    f16x8 v;
    for (int j = 0; j < 8; ++j) {
      int row = kg * 8 + j;
      v[j] = tile[row * 64 + ((((d >> 3) + kg) & 7) << 3) + (d & 7)];
    }
    int kvr = kv0 + kg * 8;
    int c = (kvr & ~127) | ((kvr + 8 * (d & 15)) & 127);
    *(f16x8*)(VT + obase + (size_t)d * T + c) = v;
  }
}

// LDS rows of 64 f16 = 8 granules; slot s of row r holds granule s^(r&7).
__device__ __forceinline__ f16x8 lds_frag(const f16* base, int row, int gr) {
  return *(const f16x8*)(base + row * 64 + ((gr ^ (row & 7)) << 3));
}

// ---------- GEMM: C = A @ Bt^T + bias, ping-pong double-buffered ----------
template <int TM, int TN, bool OUT_F32>
__global__ __launch_bounds__(256, 2) void gemm_f16_bt(const f16* __restrict__ A,
                                                      const f16* __restrict__ Bt,
                                                      const float* __restrict__ bias,
                                                      void* __restrict__ Cout,
                                                      int Nn, int Kk) {
  __shared__ f16 As[2][TM * 64];
  __shared__ f16 Bs[2][TN * 64];
  const int tid = threadIdx.x;
  const int lane = tid & 63, w = tid >> 6;
  const int quad = lane >> 4, l16 = lane & 15;
  const int wm = w >> 1, wn = w & 1;
  const int m0 = blockIdx.y * TM, n0 = blockIdx.x * TN;
  constexpr int AM = TM / 32, AN = TN / 32;

  f32x4 acc[AM][AN];
  for (int a = 0; a < AM; ++a)
    for (int b2 = 0; b2 < AN; ++b2)
      for (int r = 0; r < 4; ++r) acc[a][b2][r] = 0.f;

  auto stage = [&](int k0, int buf) {
    for (int p = 0; p < TM * 8 / 256; ++p) {
      int slot = p * 256 + w * 64 + lane;
      int r = slot >> 3, g = (slot & 7) ^ (r & 7);
      gload_lds16(A + (size_t)(m0 + r) * Kk + k0 + g * 8,
                  (char*)&As[buf][0] + (p * 256 + w * 64) * 16);
    }
    for (int p = 0; p < TN * 8 / 256; ++p) {
      int slot = p * 256 + w * 64 + lane;
      int r = slot >> 3, g = (slot & 7) ^ (r & 7);
      gload_lds16(Bt + (size_t)(n0 + r) * Kk + k0 + g * 8,
                  (char*)&Bs[buf][0] + (p * 256 + w * 64) * 16);
    }
  };

  stage(0, 0);
  __syncthreads();
  const int NIT = Kk / 64;
  for (int it = 0; it < NIT; ++it) {
    const int cur = it & 1;
    if (it + 1 < NIT) stage((it + 1) * 64, cur ^ 1);
    for (int ks = 0; ks < 2; ++ks) {
      f16x8 af[AM], bf[AN];
      for (int t = 0; t < AM; ++t)
        af[t] = lds_frag(&As[cur][0], wm * (TM / 2) + t * 16 + l16, ks * 4 + quad);
      for (int t = 0; t < AN; ++t)
        bf[t] = lds_frag(&Bs[cur][0], wn * (TN / 2) + t * 16 + l16, ks * 4 + quad);
      for (int tm = 0; tm < AM; ++tm)
        for (int tn = 0; tn < AN; ++tn)
          acc[tm][tn] = MFMA32(af[tm], bf[tn], acc[tm][tn]);
    }
    __syncthreads();
  }

  for (int tm = 0; tm < AM; ++tm)
    for (int tn = 0; tn < AN; ++tn)
      for (int r = 0; r < 4; ++r) {
        int m = m0 + wm * (TM / 2) + tm * 16 + quad * 4 + r;
        int n = n0 + wn * (TN / 2) + tn * 16 + l16;
        float v = acc[tm][tn][r] + bias[n];
        if (OUT_F32)
          ((float*)Cout)[(size_t)m * Nn + n] = v;
        else
          ((f16*)Cout)[(size_t)m * Nn + n] = (f16)v;
      }
}

// ---------- flash attention v8: tq=4 (64 q/wave) ----------
// Block = 512 thr = 4 q-waves x 2 kv-groups; 256 q/block; kv tile 128 dbuf.
// Grid (T/256=8, NH, B) = 256 blocks = 1/CU = 2 waves/SIMD. Per wave-iter:
// 64 MFMA vs 16 b128 LDS reads (4:1), 4 independent tq chains per s-block.
// K staged with permuted rows so P^T lands in MFMA32 B-operand layout; V from
// pre-rotated VT (linear DMA). l = VALU row-sum, quad-reduced at the end.

static constexpr int KT_ELE = 128 * 64;
static constexpr int VT_ELE = 64 * 128;

__global__ __launch_bounds__(512, 2) void attn_fused(const f16* __restrict__ QKV,
                                                     const f16* __restrict__ VT,
                                                     const float* __restrict__ maskf,
                                                     f16* __restrict__ ctx) {
  __shared__ __align__(16) char smem[70656];  // staging 64KB | combine 70.6KB
  f16* KtB = (f16*)smem;
  f16* VtB = (f16*)(smem + 2 * KT_ELE * 2);

  const int tid = threadIdx.x;
  const int w = tid >> 6, lane = tid & 63;
  const int quad = lane >> 4, l16 = lane & 15;
  const int qw = w & 3, g = w >> 2;
  const int q0 = blockIdx.x * 256, h = blockIdx.y, b = blockIdx.z;

  const size_t kbase = (size_t)(b * T) * NQKV + H + h * HD;
  const size_t vtbase = ((size_t)(b * NH + h) * HD) * T;
  const float* maskp = maskf + b * T;

  // Q B-frags
  f16x8 qf[4][2];
  for (int tq = 0; tq < 4; ++tq) {
    const f16* qrow = QKV + (size_t)(b * T + q0 + qw * 64 + tq * 16 + l16) * NQKV + h * HD;
    qf[tq][0] = *(const f16x8*)(qrow + quad * 8);
    qf[tq][1] = *(const f16x8*)(qrow + 32 + quad * 8);
  }

  f32x4 oacc[4][4];
  float lsum[4] = {0.f, 0.f, 0.f, 0.f};
  for (int tq = 0; tq < 4; ++tq)
    for (int t = 0; t < 4; ++t)
      for (int r = 0; r < 4; ++r) oacc[tq][t][r] = 0.f;

  auto stage = [&](int kv0, int buf) {
    f16* Kd = KtB + buf * KT_ELE;
    f16* Vd = VtB + buf * VT_ELE;
    for (int p = 0; p < 2; ++p) {
      int s = p * 512 + tid;
      int R = s >> 3, sg = (s & 7) ^ (R & 7);
      int kv = (R & ~31) | ((R & 12) << 1) | ((R & 16) >> 2) | (R & 3);
      gload_lds16(QKV + kbase + (size_t)(kv0 + kv) * NQKV + sg * 8,
                  (char*)Kd + (p * 512 + w * 64) * 16);
    }
    for (int p = 0; p < 2; ++p) {
      int s = p * 512 + tid;
      int d = s >> 4, cg = s & 15;
      gload_lds16(VT + vtbase + (size_t)d * T + kv0 + cg * 8,
                  (char*)Vd + (p * 512 + w * 64) * 16);
    }
  };

  stage(0, 0);
  __syncthreads();

  for (int it = 0; it < T / 128; ++it) {
    const int cur = it & 1;
    if (it + 1 < T / 128) stage((it + 1) * 128, cur ^ 1);

    const f16* Kc = KtB + cur * KT_ELE;
    const f16* Vc = VtB + cur * VT_ELE;

    for (int s = 0; s < 2; ++s) {
      const int bi = g * 2 + s;               // 32-kv block index in tile
      const int kvabs = it * 128 + bi * 32;
      float4 m0 = *(const float4*)(maskp + kvabs + quad * 8);
      float4 m1 = *(const float4*)(maskp + kvabs + quad * 8 + 4);
      f16x8 kfA0 = lds_frag(Kc, bi * 32 + l16, quad);
      f16x8 kfA1 = lds_frag(Kc, bi * 32 + l16, 4 + quad);
      f16x8 kfB0 = lds_frag(Kc, bi * 32 + 16 + l16, quad);
      f16x8 kfB1 = lds_frag(Kc, bi * 32 + 16 + l16, 4 + quad);
      f16x8 vf[4];
      for (int td = 0; td < 4; ++td)
        vf[td] = *(const f16x8*)&Vc[(td * 16 + l16) * 128 +
                                    ((bi * 32 + quad * 8 + 8 * l16) & 127)];
      for (int tq = 0; tq < 4; ++tq) {
        f32x4 sA = {0.f, 0.f, 0.f, 0.f}, sB = {0.f, 0.f, 0.f, 0.f};
        sA = MFMA32(kfA0, qf[tq][0], sA);
        sA = MFMA32(kfA1, qf[tq][1], sA);
        sB = MFMA32(kfB0, qf[tq][0], sB);
        sB = MFMA32(kfB1, qf[tq][1], sB);
        float pA0 = __builtin_amdgcn_exp2f(sA[0]) * m0.x;
        float pA1 = __builtin_amdgcn_exp2f(sA[1]) * m0.y;
        float pA2 = __builtin_amdgcn_exp2f(sA[2]) * m0.z;
        float pA3 = __builtin_amdgcn_exp2f(sA[3]) * m0.w;
        float pB0 = __builtin_amdgcn_exp2f(sB[0]) * m1.x;
        float pB1 = __builtin_amdgcn_exp2f(sB[1]) * m1.y;
        float pB2 = __builtin_amdgcn_exp2f(sB[2]) * m1.z;
        float pB3 = __builtin_amdgcn_exp2f(sB[3]) * m1.w;
        lsum[tq] += ((pA0 + pA1) + (pA2 + pA3)) + ((pB0 + pB1) + (pB2 + pB3));
        union PF { f16x8 v; h16x2 h[4]; } pf;
        pf.h[0] = __builtin_amdgcn_cvt_pkrtz(pA0, pA1);
        pf.h[1] = __builtin_amdgcn_cvt_pkrtz(pA2, pA3);
        pf.h[2] = __builtin_amdgcn_cvt_pkrtz(pB0, pB1);
        pf.h[3] = __builtin_amdgcn_cvt_pkrtz(pB2, pB3);
        for (int td = 0; td < 4; ++td)
          oacc[tq][td] = MFMA32(vf[td], pf.v, oacc[tq][td]);
      }
    }
    __syncthreads();
  }

  // ---- combine the 2 kv-groups (additive partials; 68 floats, stride 69) ----
  float* cmb = (float*)smem;
  const int slot = qw * 64 + lane;
  if (g == 1) {
    float* dst = cmb + slot * 69;
    int i = 0;
    for (int tq = 0; tq < 4; ++tq)
      for (int td = 0; td < 4; ++td)
        for (int r = 0; r < 4; ++r) dst[i++] = oacc[tq][td][r];
    for (int tq = 0; tq < 4; ++tq) dst[64 + tq] = lsum[tq];
  }
  __syncthreads();
  if (g == 0) {
    const float* src = cmb + slot * 69;
    int i = 0;
    for (int tq = 0; tq < 4; ++tq)
      for (int td = 0; td < 4; ++td)
        for (int r = 0; r < 4; ++r) oacc[tq][td][r] += src[i++];
    for (int tq = 0; tq < 4; ++tq) lsum[tq] += src[64 + tq];

    for (int tq = 0; tq < 4; ++tq) {
      float l = lsum[tq];
      l += __shfl_xor(l, 16, 64);
      l += __shfl_xor(l, 32, 64);
      float inv = 1.f / l;
      int row = b * T + q0 + qw * 64 + tq * 16 + l16;
      for (int td = 0; td < 4; ++td) {
        f16x4 o;
        for (int r = 0; r < 4; ++r) o[r] = (f16)(oacc[tq][td][r] * inv);
        *(f16x4*)(ctx + (size_t)row * H + h * HD + td * 16 + quad * 4) = o;
      }
    }
  }
}

// ---------- launch ----------

extern "C" void kernel_launch(void* const* d_in, const int* in_sizes, int n_in,
                              void* d_out, int out_size, void* d_ws, size_t ws_size,
                              hipStream_t stream) {
  const float* x  = (const float*)d_in[0];
  const int* mask = (const int*)d_in[1];
  const float* Wq = (const float*)d_in[2];
  const float* bq = (const float*)d_in[3];
  const float* Wk = (const float*)d_in[4];
  const float* bk = (const float*)d_in[5];
  const float* Wv = (const float*)d_in[6];
  const float* bv = (const float*)d_in[7];
  const float* Wo = (const float*)d_in[8];
  const float* bo = (const float*)d_in[9];
  float* out = (float*)d_out;

  char* ws = (char*)d_ws;
  f16* xh      = (f16*)(ws);                            // 8 MB
  f16* Wqkv_t  = (f16*)(ws + (8u  << 20));              // 6 MB
  f16* Wot     = (f16*)(ws + (14u << 20));              // 2 MB
  float* bqkv  = (float*)(ws + (16u << 20));            // 12 KB
  float* maskf = (float*)(ws + (16u << 20) + 65536);    // 16 KB
  f16* QKV     = (f16*)(ws + (17u << 20));              // 24 MB
  f16* ctx     = (f16*)(ws + (42u << 20));              // 8 MB
  f16* VTr     = (f16*)(ws + (50u << 20));              // 8 MB [B][NH][64][T]

  pack_all<<<dim3(5164), 256, 0, stream>>>(x, Wq, Wk, Wv, Wo, bq, bk, bv, mask,
                                           xh, Wqkv_t, Wot, bqkv, maskf);

  gemm_f16_bt<128, 128, false><<<dim3(NQKV / 128, M / 128), 256, 0, stream>>>(
      xh, Wqkv_t, bqkv, QKV, NQKV, H);

  vtrans<<<dim3(T / 64, NH, Bb), 256, 0, stream>>>(QKV, VTr);

  attn_fused<<<dim3(T / 256, NH, Bb), 512, 0, stream>>>(QKV, VTr, maskf, ctx);

  gemm_f16_bt<128, 64, true><<<dim3(H / 64, M / 128), 256, 0, stream>>>(
      ctx, Wot, bo, out, H, H);
}

// Round 10
// 191.439 us; speedup vs baseline: 1.1597x; 1.0230x over previous
//
#include <hip/hip_runtime.h>

typedef _Float16 f16;
typedef _Float16 f16x8 __attribute__((ext_vector_type(8)));
typedef _Float16 f16x4 __attribute__((ext_vector_type(4)));
typedef __fp16 h16x2 __attribute__((ext_vector_type(2)));
typedef float f32x4 __attribute__((ext_vector_type(4)));

#define MFMA32(a, b, c) __builtin_amdgcn_mfma_f32_16x16x32_f16((a), (b), (c), 0, 0, 0)

static constexpr int Bb = 2, T = 2048, H = 1024, NH = 16, HD = 64;
static constexpr int M = Bb * T;      // 4096 rows
static constexpr int NQK = 2 * H;     // QK buffer row stride (Q | K)
// fold 1/sqrt(64) * log2(e) into Wq/bq so P = 2^S via raw v_exp_f32
#define QSCALE 0.1803368801111f

__device__ __forceinline__ void gload_lds16(const void* g, void* l) {
  __builtin_amdgcn_global_load_lds(
      (const __attribute__((address_space(1))) void*)g,
      (__attribute__((address_space(3))) void*)l, 16, 0, 0);
}

// ---------- fused pack kernel ----------
__global__ __launch_bounds__(256) void pack_all(const float* __restrict__ x,
                                                const float* __restrict__ Wq,
                                                const float* __restrict__ Wk,
                                                const float* __restrict__ Wv,
                                                const float* __restrict__ Wo,
                                                const float* __restrict__ bq,
                                                const float* __restrict__ bk,
                                                const float* __restrict__ bv,
                                                const int* __restrict__ mask,
                                                f16* __restrict__ xh,
                                                f16* __restrict__ WqkvT,
                                                f16* __restrict__ WoT,
                                                float* __restrict__ bqkv,
                                                float* __restrict__ maskf) {
  __shared__ f16 tile[64][65];
  const int bid = blockIdx.x;
  if (bid < 4096) {
    int i = bid * 256 + threadIdx.x;
    float4 v = ((const float4*)x)[i];
    f16x4 o;
    o[0] = (f16)v.x; o[1] = (f16)v.y; o[2] = (f16)v.z; o[3] = (f16)v.w;
    *(f16x4*)(xh + (size_t)i * 4) = o;
  } else if (bid < 5120) {
    int t = bid - 4096;
    int z = t >> 8, rem = t & 255;
    const float* W = (z == 0) ? Wq : (z == 1) ? Wk : (z == 2) ? Wv : Wo;
    f16* Wt = (z < 3) ? (WqkvT + (size_t)z * H * H) : WoT;
    const float scale = (z == 0) ? QSCALE : 1.0f;
    int k0 = (rem >> 4) * 64, n0 = (rem & 15) * 64;
    for (int p = 0; p < 16; ++p) {
      int idx = threadIdx.x + p * 256;
      int r = idx >> 6, c = idx & 63;
      tile[r][c] = (f16)(W[(size_t)(k0 + r) * H + n0 + c] * scale);
    }
    __syncthreads();
    for (int p = 0; p < 16; ++p) {
      int idx = threadIdx.x + p * 256;
      int r = idx >> 6, c = idx & 63;
      Wt[(size_t)(n0 + r) * H + k0 + c] = tile[c][r];
    }
  } else if (bid < 5132) {
    int i = (bid - 5120) * 256 + threadIdx.x;
    if (i < 3072) {
      float v = (i < 1024) ? bq[i] * QSCALE : ((i < 2048) ? bk[i - 1024] : bv[i - 2048]);
      bqkv[i] = v;
    }
  } else {
    int i = (bid - 5132) * 256 + threadIdx.x;
    if (i < Bb * T) maskf[i] = mask[i] ? 1.0f : 0.0f;
  }
}

// LDS rows of 64 f16 = 8 granules; slot s of row r holds granule s^(r&7).
__device__ __forceinline__ f16x8 lds_frag(const f16* base, int row, int gr) {
  return *(const f16x8*)(base + row * 64 + ((gr ^ (row & 7)) << 3));
}

// ---------- GEMM1: [xh @ WqkvT^T + b] -> QK (n<2048) / VT transposed (n>=2048)
// TM=128, TN=64, 3 blocks/CU, ping-pong dbuf staging. V epilogue writes the
// pre-rotated transposed layout VT[b][h][d][c], c=(t&~127)|((t+8*(d&15))&127).
__global__ __launch_bounds__(256, 3) void gemm_qkv(const f16* __restrict__ A,
                                                   const f16* __restrict__ Bt,
                                                   const float* __restrict__ bias,
                                                   f16* __restrict__ QK,
                                                   f16* __restrict__ VT) {
  constexpr int TM = 128, TN = 64, Kk = 1024;
  __shared__ f16 As[2][TM * 64];
  __shared__ f16 Bs[2][TN * 64];
  const int tid = threadIdx.x;
  const int lane = tid & 63, w = tid >> 6;
  const int quad = lane >> 4, l16 = lane & 15;
  const int wm = w >> 1, wn = w & 1;
  const int m0 = blockIdx.y * TM, n0 = blockIdx.x * TN;

  f32x4 acc[4][2];
  for (int a = 0; a < 4; ++a)
    for (int b2 = 0; b2 < 2; ++b2)
      for (int r = 0; r < 4; ++r) acc[a][b2][r] = 0.f;

  auto stage = [&](int k0, int buf) {
    for (int p = 0; p < 4; ++p) {
      int slot = p * 256 + w * 64 + lane;
      int r = slot >> 3, g = (slot & 7) ^ (r & 7);
      gload_lds16(A + (size_t)(m0 + r) * Kk + k0 + g * 8,
                  (char*)&As[buf][0] + (p * 256 + w * 64) * 16);
    }
    for (int p = 0; p < 2; ++p) {
      int slot = p * 256 + w * 64 + lane;
      int r = slot >> 3, g = (slot & 7) ^ (r & 7);
      gload_lds16(Bt + (size_t)(n0 + r) * Kk + k0 + g * 8,
                  (char*)&Bs[buf][0] + (p * 256 + w * 64) * 16);
    }
  };

  stage(0, 0);
  __syncthreads();
  for (int it = 0; it < Kk / 64; ++it) {
    const int cur = it & 1;
    if (it + 1 < Kk / 64) stage((it + 1) * 64, cur ^ 1);
    for (int ks = 0; ks < 2; ++ks) {
      f16x8 af[4], bf[2];
      for (int t = 0; t < 4; ++t)
        af[t] = lds_frag(&As[cur][0], wm * 64 + t * 16 + l16, ks * 4 + quad);
      for (int t = 0; t < 2; ++t)
        bf[t] = lds_frag(&Bs[cur][0], wn * 32 + t * 16 + l16, ks * 4 + quad);
      for (int tm = 0; tm < 4; ++tm)
        for (int tn = 0; tn < 2; ++tn)
          acc[tm][tn] = MFMA32(af[tm], bf[tn], acc[tm][tn]);
    }
    __syncthreads();
  }

  if (n0 < 2048) {
    for (int tm = 0; tm < 4; ++tm)
      for (int tn = 0; tn < 2; ++tn) {
        int n = n0 + wn * 32 + tn * 16 + l16;
        float bn = bias[n];
        for (int r = 0; r < 4; ++r) {
          int m = m0 + wm * 64 + tm * 16 + quad * 4 + r;
          QK[(size_t)m * NQK + n] = (f16)(acc[tm][tn][r] + bn);
        }
      }
  } else {
    for (int tm = 0; tm < 4; ++tm)
      for (int tn = 0; tn < 2; ++tn) {
        int ng = n0 + wn * 32 + tn * 16 + l16;
        float bn = bias[ng];
        int n = ng - 2048;
        int h = n >> 6, d = n & 63;
        int mrow = m0 + wm * 64 + tm * 16 + quad * 4;
        int bb = mrow >> 11, t = mrow & 2047;
        int c = (t & ~127) | ((t + 8 * (d & 15)) & 127);
        f16x4 o;
        for (int r = 0; r < 4; ++r) o[r] = (f16)(acc[tm][tn][r] + bn);
        *(f16x4*)(VT + ((size_t)(bb * NH + h) * HD + d) * T + c) = o;
      }
  }
}

// ---------- GEMM2: out = ctx @ WoT^T + bo (f32 out) ----------
__global__ __launch_bounds__(256, 3) void gemm_out(const f16* __restrict__ A,
                                                   const f16* __restrict__ Bt,
                                                   const float* __restrict__ bias,
                                                   float* __restrict__ Cout) {
  constexpr int TM = 128, TN = 64, Kk = 1024, Nn = 1024;
  __shared__ f16 As[2][TM * 64];
  __shared__ f16 Bs[2][TN * 64];
  const int tid = threadIdx.x;
  const int lane = tid & 63, w = tid >> 6;
  const int quad = lane >> 4, l16 = lane & 15;
  const int wm = w >> 1, wn = w & 1;
  const int m0 = blockIdx.y * TM, n0 = blockIdx.x * TN;

  f32x4 acc[4][2];
  for (int a = 0; a < 4; ++a)
    for (int b2 = 0; b2 < 2; ++b2)
      for (int r = 0; r < 4; ++r) acc[a][b2][r] = 0.f;

  auto stage = [&](int k0, int buf) {
    for (int p = 0; p < 4; ++p) {
      int slot = p * 256 + w * 64 + lane;
      int r = slot >> 3, g = (slot & 7) ^ (r & 7);
      gload_lds16(A + (size_t)(m0 + r) * Kk + k0 + g * 8,
                  (char*)&As[buf][0] + (p * 256 + w * 64) * 16);
    }
    for (int p = 0; p < 2; ++p) {
      int slot = p * 256 + w * 64 + lane;
      int r = slot >> 3, g = (slot & 7) ^ (r & 7);
      gload_lds16(Bt + (size_t)(n0 + r) * Kk + k0 + g * 8,
                  (char*)&Bs[buf][0] + (p * 256 + w * 64) * 16);
    }
  };

  stage(0, 0);
  __syncthreads();
  for (int it = 0; it < Kk / 64; ++it) {
    const int cur = it & 1;
    if (it + 1 < Kk / 64) stage((it + 1) * 64, cur ^ 1);
    for (int ks = 0; ks < 2; ++ks) {
      f16x8 af[4], bf[2];
      for (int t = 0; t < 4; ++t)
        af[t] = lds_frag(&As[cur][0], wm * 64 + t * 16 + l16, ks * 4 + quad);
      for (int t = 0; t < 2; ++t)
        bf[t] = lds_frag(&Bs[cur][0], wn * 32 + t * 16 + l16, ks * 4 + quad);
      for (int tm = 0; tm < 4; ++tm)
        for (int tn = 0; tn < 2; ++tn)
          acc[tm][tn] = MFMA32(af[tm], bf[tn], acc[tm][tn]);
    }
    __syncthreads();
  }

  for (int tm = 0; tm < 4; ++tm)
    for (int tn = 0; tn < 2; ++tn) {
      int n = n0 + wn * 32 + tn * 16 + l16;
      float bn = bias[n];
      for (int r = 0; r < 4; ++r) {
        int m = m0 + wm * 64 + tm * 16 + quad * 4 + r;
        Cout[(size_t)m * Nn + n] = acc[tm][tn][r] + bn;
      }
    }
}

// ---------- flash attention v9: phase-split ILP ----------
// Block = 512 thr = 4 q-waves x 2 kv-groups; 256 q/block; kv tile 128 dbuf.
// Per 32-kv block: ALL 16 QK MFMAs issued first, then all softmax VALU, then
// all 16 PV MFMAs -- flat independent streams keep the MFMA pipe fed during
// VALU phases (and PV(s) overlaps QK(s+1)). K from QK buffer (stride 2048),
// V from pre-rotated VT written by gemm_qkv. l = VALU row-sum.

static constexpr int KT_ELE = 128 * 64;
static constexpr int VT_ELE = 64 * 128;

__global__ __launch_bounds__(512, 2) void attn_fused(const f16* __restrict__ QK,
                                                     const f16* __restrict__ VT,
                                                     const float* __restrict__ maskf,
                                                     f16* __restrict__ ctx) {
  __shared__ __align__(16) char smem[70656];  // staging 64KB | combine 70.6KB
  f16* KtB = (f16*)smem;
  f16* VtB = (f16*)(smem + 2 * KT_ELE * 2);

  const int tid = threadIdx.x;
  const int w = tid >> 6, lane = tid & 63;
  const int quad = lane >> 4, l16 = lane & 15;
  const int qw = w & 3, g = w >> 2;
  const int q0 = blockIdx.x * 256, h = blockIdx.y, b = blockIdx.z;

  const size_t kbase = (size_t)(b * T) * NQK + H + h * HD;
  const size_t vtbase = ((size_t)(b * NH + h) * HD) * T;
  const float* maskp = maskf + b * T;

  // Q B-frags
  f16x8 qf[4][2];
  for (int tq = 0; tq < 4; ++tq) {
    const f16* qrow = QK + (size_t)(b * T + q0 + qw * 64 + tq * 16 + l16) * NQK + h * HD;
    qf[tq][0] = *(const f16x8*)(qrow + quad * 8);
    qf[tq][1] = *(const f16x8*)(qrow + 32 + quad * 8);
  }

  f32x4 oacc[4][4];
  float lsum[4] = {0.f, 0.f, 0.f, 0.f};
  for (int tq = 0; tq < 4; ++tq)
    for (int t = 0; t < 4; ++t)
      for (int r = 0; r < 4; ++r) oacc[tq][t][r] = 0.f;

  auto stage = [&](int kv0, int buf) {
    f16* Kd = KtB + buf * KT_ELE;
    f16* Vd = VtB + buf * VT_ELE;
    for (int p = 0; p < 2; ++p) {
      int s = p * 512 + tid;
      int R = s >> 3, sg = (s & 7) ^ (R & 7);
      int kv = (R & ~31) | ((R & 12) << 1) | ((R & 16) >> 2) | (R & 3);
      gload_lds16(QK + kbase + (size_t)(kv0 + kv) * NQK + sg * 8,
                  (char*)Kd + (p * 512 + w * 64) * 16);
    }
    for (int p = 0; p < 2; ++p) {
      int s = p * 512 + tid;
      int d = s >> 4, cg = s & 15;
      gload_lds16(VT + vtbase + (size_t)d * T + kv0 + cg * 8,
                  (char*)Vd + (p * 512 + w * 64) * 16);
    }
  };

  stage(0, 0);
  __syncthreads();

  for (int it = 0; it < T / 128; ++it) {
    const int cur = it & 1;
    if (it + 1 < T / 128) stage((it + 1) * 128, cur ^ 1);

    const f16* Kc = KtB + cur * KT_ELE;
    const f16* Vc = VtB + cur * VT_ELE;

    for (int s = 0; s < 2; ++s) {
      const int bi = g * 2 + s;               // 32-kv block index in tile
      const int kvabs = it * 128 + bi * 32;
      float4 m0 = *(const float4*)(maskp + kvabs + quad * 8);
      float4 m1 = *(const float4*)(maskp + kvabs + quad * 8 + 4);
      f16x8 kfA0 = lds_frag(Kc, bi * 32 + l16, quad);
      f16x8 kfA1 = lds_frag(Kc, bi * 32 + l16, 4 + quad);
      f16x8 kfB0 = lds_frag(Kc, bi * 32 + 16 + l16, quad);
      f16x8 kfB1 = lds_frag(Kc, bi * 32 + 16 + l16, 4 + quad);
      f16x8 vf[4];
      for (int td = 0; td < 4; ++td)
        vf[td] = *(const f16x8*)&Vc[(td * 16 + l16) * 128 +
                                    ((bi * 32 + quad * 8 + 8 * l16) & 127)];

      // phase 1: all QK MFMAs (16, independent chains of 2)
      f32x4 sA[4], sB[4];
      for (int tq = 0; tq < 4; ++tq) {
        f32x4 z = {0.f, 0.f, 0.f, 0.f};
        sA[tq] = MFMA32(kfA0, qf[tq][0], z);
        sB[tq] = MFMA32(kfB0, qf[tq][0], z);
      }
      for (int tq = 0; tq < 4; ++tq) {
        sA[tq] = MFMA32(kfA1, qf[tq][1], sA[tq]);
        sB[tq] = MFMA32(kfB1, qf[tq][1], sB[tq]);
      }

      // phase 2: softmax VALU (all tq)
      f16x8 pf[4];
      for (int tq = 0; tq < 4; ++tq) {
        float pA0 = __builtin_amdgcn_exp2f(sA[tq][0]) * m0.x;
        float pA1 = __builtin_amdgcn_exp2f(sA[tq][1]) * m0.y;
        float pA2 = __builtin_amdgcn_exp2f(sA[tq][2]) * m0.z;
        float pA3 = __builtin_amdgcn_exp2f(sA[tq][3]) * m0.w;
        float pB0 = __builtin_amdgcn_exp2f(sB[tq][0]) * m1.x;
        float pB1 = __builtin_amdgcn_exp2f(sB[tq][1]) * m1.y;
        float pB2 = __builtin_amdgcn_exp2f(sB[tq][2]) * m1.z;
        float pB3 = __builtin_amdgcn_exp2f(sB[tq][3]) * m1.w;
        lsum[tq] += ((pA0 + pA1) + (pA2 + pA3)) + ((pB0 + pB1) + (pB2 + pB3));
        union PF { f16x8 v; h16x2 h[4]; } u;
        u.h[0] = __builtin_amdgcn_cvt_pkrtz(pA0, pA1);
        u.h[1] = __builtin_amdgcn_cvt_pkrtz(pA2, pA3);
        u.h[2] = __builtin_amdgcn_cvt_pkrtz(pB0, pB1);
        u.h[3] = __builtin_amdgcn_cvt_pkrtz(pB2, pB3);
        pf[tq] = u.v;
      }

      // phase 3: all PV MFMAs (16, independent accumulators)
      for (int tq = 0; tq < 4; ++tq)
        for (int td = 0; td < 4; ++td)
          oacc[tq][td] = MFMA32(vf[td], pf[tq], oacc[tq][td]);
    }
    __syncthreads();
  }

  // ---- combine the 2 kv-groups (additive partials; 68 floats, stride 69) ----
  float* cmb = (float*)smem;
  const int slot = qw * 64 + lane;
  if (g == 1) {
    float* dst = cmb + slot * 69;
    int i = 0;
    for (int tq = 0; tq < 4; ++tq)
      for (int td = 0; td < 4; ++td)
        for (int r = 0; r < 4; ++r) dst[i++] = oacc[tq][td][r];
    for (int tq = 0; tq < 4; ++tq) dst[64 + tq] = lsum[tq];
  }
  __syncthreads();
  if (g == 0) {
    const float* src = cmb + slot * 69;
    int i = 0;
    for (int tq = 0; tq < 4; ++tq)
      for (int td = 0; td < 4; ++td)
        for (int r = 0; r < 4; ++r) oacc[tq][td][r] += src[i++];
    for (int tq = 0; tq < 4; ++tq) lsum[tq] += src[64 + tq];

    for (int tq = 0; tq < 4; ++tq) {
      float l = lsum[tq];
      l += __shfl_xor(l, 16, 64);
      l += __shfl_xor(l, 32, 64);
      float inv = 1.f / l;
      int row = b * T + q0 + qw * 64 + tq * 16 + l16;
      for (int td = 0; td < 4; ++td) {
        f16x4 o;
        for (int r = 0; r < 4; ++r) o[r] = (f16)(oacc[tq][td][r] * inv);
        *(f16x4*)(ctx + (size_t)row * H + h * HD + td * 16 + quad * 4) = o;
      }
    }
  }
}

// ---------- launch ----------

extern "C" void kernel_launch(void* const* d_in, const int* in_sizes, int n_in,
                              void* d_out, int out_size, void* d_ws, size_t ws_size,
                              hipStream_t stream) {
  const float* x  = (const float*)d_in[0];
  const int* mask = (const int*)d_in[1];
  const float* Wq = (const float*)d_in[2];
  const float* bq = (const float*)d_in[3];
  const float* Wk = (const float*)d_in[4];
  const float* bk = (const float*)d_in[5];
  const float* Wv = (const float*)d_in[6];
  const float* bv = (const float*)d_in[7];
  const float* Wo = (const float*)d_in[8];
  const float* bo = (const float*)d_in[9];
  float* out = (float*)d_out;

  char* ws = (char*)d_ws;
  f16* xh      = (f16*)(ws);                            // 8 MB
  f16* Wqkv_t  = (f16*)(ws + (8u  << 20));              // 6 MB
  f16* Wot     = (f16*)(ws + (14u << 20));              // 2 MB
  float* bqkv  = (float*)(ws + (16u << 20));            // 12 KB
  float* maskf = (float*)(ws + (16u << 20) + 65536);    // 16 KB
  f16* QK      = (f16*)(ws + (17u << 20));              // 16 MB [4096][2048]
  f16* ctx     = (f16*)(ws + (34u << 20));              // 8 MB
  f16* VTr     = (f16*)(ws + (43u << 20));              // 8 MB [B][NH][64][T]

  pack_all<<<dim3(5164), 256, 0, stream>>>(x, Wq, Wk, Wv, Wo, bq, bk, bv, mask,
                                           xh, Wqkv_t, Wot, bqkv, maskf);

  gemm_qkv<<<dim3(3 * H / 64, M / 128), 256, 0, stream>>>(
      xh, Wqkv_t, bqkv, QK, VTr);

  attn_fused<<<dim3(T / 256, NH, Bb), 512, 0, stream>>>(QK, VTr, maskf, ctx);

  gemm_out<<<dim3(H / 64, M / 128), 256, 0, stream>>>(ctx, Wot, bo, out);
}